// Round 2
// baseline (1047.943 us; speedup 1.0000x reference)
//
#include <hip/hip_runtime.h>
#include <hip/hip_fp16.h>

#define N_PTS   100000
#define KNB     16
#define CIN     128
#define COUT    256
#define NKP     15
#define CCH     131          // CIN + 3
#define KFLAT   1965         // NKP * CCH
#define KP      1984         // padded K (62 * 32)
#define MPAD    100096       // 782 * 128

typedef _Float16 f16x8 __attribute__((ext_vector_type(8)));
typedef float    f32x4 __attribute__((ext_vector_type(4)));

__device__ __forceinline__ void g2lds16(const void* g, void* l) {
  __builtin_amdgcn_global_load_lds((const __attribute__((address_space(1))) void*)g,
                                   (__attribute__((address_space(3))) void*)l, 16, 0, 0);
}

// ---------------- prep: W repack + BN fold ----------------
__global__ __launch_bounds__(256) void k_prep_w(
    const float* __restrict__ w, const float* __restrict__ cb,
    const float* __restrict__ g, const float* __restrict__ be,
    const float* __restrict__ mu, const float* __restrict__ var,
    __half* __restrict__ wt, float* __restrict__ sc, float* __restrict__ sh) {
  int gid = blockIdx.x * 256 + threadIdx.x;         // COUT*KP threads
  int o = gid / KP, r = gid - o * KP;
  float v = 0.f;
  if (r < KFLAT) {
    int m = r / CCH, c = r - m * CCH;
    v = w[(o * CCH + c) * NKP + m];                 // conv_w[o][c][m]
  }
  wt[gid] = __float2half(v);
  if (gid < COUT) {
    float s = g[gid] / sqrtf(var[gid] + 1e-5f);
    sc[gid] = s;
    sh[gid] = (cb[gid] - mu[gid]) * s + be[gid];
  }
}

// ---------------- agg: per-point gather + corr + aggregate ----------------
// one wave per point; chunk starts at row r0, writes agg[(n - r0)][*]
__global__ __launch_bounds__(256) void k_agg(
    const float* __restrict__ p, const float* __restrict__ x,
    const float* __restrict__ kp, const int* __restrict__ idx,
    __half* __restrict__ agg, int r0) {
  __shared__ float pj_lds[4][16][3];
  const int l = threadIdx.x & 63;
  const int w = threadIdx.x >> 6;
  const int n = r0 + blockIdx.x * 4 + w;            // global point id (may exceed N_PTS on last chunk)
  const int nc = (n < N_PTS) ? n : (N_PTS - 1);     // clamped for all reads
  const int k = l & 15;
  const int nbr = idx[nc * KNB + k];
  const float cx = p[nc * 3], cy = p[nc * 3 + 1], cz = p[nc * 3 + 2];
  float ax = p[nbr * 3]     - cx;
  float ay = p[nbr * 3 + 1] - cy;
  float az = p[nbr * 3 + 2] - cz;
  float l2 = sqrtf(ax * ax + ay * ay + az * az);
  float mx = l2;
  #pragma unroll
  for (int d = 1; d < 16; d <<= 1) mx = fmaxf(mx, __shfl_xor(mx, d));
  const float inv = 1.f / (mx + 1e-10f);
  ax *= inv; ay *= inv; az *= inv;

  float corr[NKP];
  #pragma unroll
  for (int m = 0; m < NKP; m++) {
    float dx = kp[m * 3] - ax, dy = kp[m * 3 + 1] - ay, dz = kp[m * 3 + 2] - az;
    corr[m] = __expf((dx * dx + dy * dy + dz * dz) * -5.5555553f);  // -1/(2*sigma^2)
  }
  if (l < 16) { pj_lds[w][l][0] = ax; pj_lds[w][l][1] = ay; pj_lds[w][l][2] = az; }
  __syncthreads();

  float acc[NKP][3];
  #pragma unroll
  for (int m = 0; m < NKP; m++) { acc[m][0] = 0.f; acc[m][1] = 0.f; acc[m][2] = 0.f; }

  // channel slots per lane: c = l, l+64, l+128 (c<3 -> pj, 3..130 -> x[c-3], >=131 inert)
  #pragma unroll
  for (int kc = 0; kc < KNB; kc += 4) {
    float xv[4][3];
    #pragma unroll
    for (int d = 0; d < 4; d++) {
      const int kk = kc + d;
      const int nb = __shfl(nbr, kk);
      const float* xr = x + (size_t)nb * CIN;
      xv[d][0] = (l < 3) ? pj_lds[w][kk][l] : xr[l - 3];
      xv[d][1] = xr[l + 61];
      xv[d][2] = (l < 3) ? xr[l + 125] : 0.f;
    }
    #pragma unroll
    for (int m = 0; m < NKP; m++) {
      #pragma unroll
      for (int d = 0; d < 4; d++) {
        const float cm = __shfl(corr[m], kc + d);
        acc[m][0] += cm * xv[d][0];
        acc[m][1] += cm * xv[d][1];
        acc[m][2] += cm * xv[d][2];
      }
    }
  }

  if (n < N_PTS) {
    __half* ar = agg + (size_t)(n - r0) * KP;
    #pragma unroll
    for (int m = 0; m < NKP; m++) {
      const int c0 = m * CCH;
      ar[c0 + l]      = __float2half(acc[m][0]);
      ar[c0 + 64 + l] = __float2half(acc[m][1]);
      if (l < 3) ar[c0 + 128 + l] = __float2half(acc[m][2]);
    }
    if (l < KP - KFLAT) ar[KFLAT + l] = __float2half(0.f);
  }
}

// ---------------- GEMM: chunk of [rows,KP] x [COUT,KP]^T + BN + ReLU ----------------
__global__ __launch_bounds__(256) void k_gemm(
    const __half* __restrict__ A, const __half* __restrict__ B,
    const float* __restrict__ sc, const float* __restrict__ sh,
    float* __restrict__ out, int r0) {
  __shared__ __align__(16) __half Al[128 * 64];
  __shared__ __align__(16) __half Bl[128 * 64];
  const int t = threadIdx.x;
  const int l = t & 63;
  const int bn = blockIdx.x, bm = blockIdx.y;
  const int m0 = bm * 128, n0 = bn * 128;           // m0 is chunk-local
  const int w = t >> 6;
  const int wm = w >> 1, wn = w & 1;

  f32x4 acc[4][4] = {};

  // staging: thread t covers rows arow+i*32, 16B slot kb; swizzled global source
  const int arow = t >> 3;                 // 0..31
  const int kb   = (t & 7) << 4;           // byte slot in 128B row
  const int kbsw = kb ^ ((arow & 7) << 4); // pre-swizzled source column (involution)
  const char* aSrc = (const char*)(A + (size_t)(m0 + arow) * KP) + kbsw;
  const char* bSrc = (const char*)(B + (size_t)(n0 + arow) * KP) + kbsw;
  char* aDst = (char*)Al + t * 16;
  char* bDst = (char*)Bl + t * 16;
  const size_t rowStride32 = (size_t)32 * KP * 2;

  for (int kt = 0; kt < KP / 64; kt++) {
    __syncthreads();
    #pragma unroll
    for (int i = 0; i < 4; i++) {
      g2lds16(aSrc + i * rowStride32 + (size_t)kt * 128, aDst + i * 4096);
      g2lds16(bSrc + i * rowStride32 + (size_t)kt * 128, bDst + i * 4096);
    }
    __syncthreads();
    #pragma unroll
    for (int kk = 0; kk < 2; kk++) {
      f16x8 af[4], bf[4];
      const int rbyte = ((l >> 4) << 4) + kk * 64;
      #pragma unroll
      for (int i = 0; i < 4; i++) {
        const int ra = wm * 64 + i * 16 + (l & 15);
        af[i] = *(const f16x8*)((const char*)Al + ra * 128 + (rbyte ^ ((ra & 7) << 4)));
        const int rb = wn * 64 + i * 16 + (l & 15);
        bf[i] = *(const f16x8*)((const char*)Bl + rb * 128 + (rbyte ^ ((rb & 7) << 4)));
      }
      #pragma unroll
      for (int i = 0; i < 4; i++)
        #pragma unroll
        for (int j = 0; j < 4; j++)
          acc[i][j] = __builtin_amdgcn_mfma_f32_16x16x32_f16(af[i], bf[j], acc[i][j], 0, 0, 0);
    }
  }

  #pragma unroll
  for (int j = 0; j < 4; j++) {
    const int col = n0 + wn * 64 + j * 16 + (l & 15);
    const float s = sc[col], h = sh[col];
    #pragma unroll
    for (int i = 0; i < 4; i++) {
      const int rr = r0 + m0 + wm * 64 + i * 16 + ((l >> 4) << 2);
      #pragma unroll
      for (int rg = 0; rg < 4; rg++) {
        const int r = rr + rg;
        if (r < N_PTS) {
          float v = acc[i][j][rg] * s + h;
          out[(size_t)r * COUT + col] = fmaxf(v, 0.f);
        }
      }
    }
  }
}

extern "C" void kernel_launch(void* const* d_in, const int* in_sizes, int n_in,
                              void* d_out, int out_size, void* d_ws, size_t ws_size,
                              hipStream_t stream) {
  (void)in_sizes; (void)n_in; (void)out_size;
  const float* p   = (const float*)d_in[0];
  const float* x   = (const float*)d_in[1];
  const float* kp  = (const float*)d_in[2];
  const float* w   = (const float*)d_in[3];
  const float* cb  = (const float*)d_in[4];
  const float* g   = (const float*)d_in[5];
  const float* be  = (const float*)d_in[6];
  const float* mu  = (const float*)d_in[7];
  const float* var = (const float*)d_in[8];
  const int* idx   = (const int*)d_in[9];
  float* out = (float*)d_out;

  char* ws = (char*)d_ws;
  size_t off = 0;
  __half* wt  = (__half*)(ws + off); off += (size_t)COUT * KP * 2;   // ~1.0 MB
  float*  sc  = (float*)(ws + off);  off += 1024;
  float*  sh  = (float*)(ws + off);  off += 1024;
  __half* agg = (__half*)(ws + off);
  size_t avail = (ws_size > off) ? (ws_size - off) : 0;

  // rows per chunk: as many 128-row tiles as fit in the remaining workspace
  size_t maxrows = avail / ((size_t)KP * 2);
  int rows;
  if (maxrows >= (size_t)MPAD) rows = MPAD;
  else rows = (int)(maxrows & ~(size_t)127);
  if (rows < 128) rows = 128;   // nothing sane possible below this; best effort

  hipLaunchKernelGGL(k_prep_w, dim3(COUT * KP / 256), dim3(256), 0, stream,
                     w, cb, g, be, mu, var, wt, sc, sh);

  for (int row0 = 0; row0 < N_PTS; row0 += rows) {
    int rr = MPAD - row0;
    if (rr > rows) rr = rows;                       // rr is a multiple of 128
    hipLaunchKernelGGL(k_agg, dim3(rr / 4), dim3(256), 0, stream, p, x, kp, idx, agg, row0);
    hipLaunchKernelGGL(k_gemm, dim3(2, rr / 128), dim3(256), 0, stream, agg, wt, sc, sh, out, row0);
  }
}

// Round 4
// 674.214 us; speedup vs baseline: 1.5543x; 1.5543x over previous
//
#include <hip/hip_runtime.h>
#include <hip/hip_fp16.h>

#define N_PTS   100000
#define KNB     16
#define CIN     128
#define COUT    256
#define NKP     15
#define CCH     131
#define MSTR    136          // per-kernel-point padded stride (8-elem aligned)
#define KP      2048         // 15*136 = 2040, padded to 2048 (32 x 64)
#define MPAD    100096       // 782 * 128

typedef _Float16 f16x8 __attribute__((ext_vector_type(8)));
typedef float    f32x4 __attribute__((ext_vector_type(4)));
typedef int      i32x4 __attribute__((ext_vector_type(4)));

__device__ __forceinline__ void g2lds16(const void* g, void* l) {
  __builtin_amdgcn_global_load_lds((const __attribute__((address_space(1))) void*)g,
                                   (__attribute__((address_space(3))) void*)l, 16, 0, 0);
}

// ---------------- prep: W repack + BN fold ----------------
// wt[o][m*136+c]: c<128 -> w[o][c+3][m] (x-part), c=128..130 -> w[o][c-128][m] (pj), else 0
__global__ __launch_bounds__(256) void k_prep_w(
    const float* __restrict__ w, const float* __restrict__ cb,
    const float* __restrict__ g, const float* __restrict__ be,
    const float* __restrict__ mu, const float* __restrict__ var,
    __half* __restrict__ wt, float* __restrict__ sc, float* __restrict__ sh) {
  int gid = blockIdx.x * 256 + threadIdx.x;         // COUT*KP threads
  int o = gid / KP, r = gid - o * KP;
  float v = 0.f;
  if (r < NKP * MSTR) {
    int m = r / MSTR, c = r - m * MSTR;
    if (c < 128)      v = w[(o * CCH + (c + 3)) * NKP + m];
    else if (c < 131) v = w[(o * CCH + (c - 128)) * NKP + m];
  }
  wt[gid] = __float2half(v);
  if (gid < COUT) {
    float s = g[gid] / sqrtf(var[gid] + 1e-5f);
    sc[gid] = s;
    sh[gid] = (cb[gid] - mu[gid]) * s + be[gid];
  }
}

// ---------------- agg: per-point gather + corr + aggregate ----------------
// one wave per point; lane owns channels 2l,2l+1; corr broadcast via readlane
__global__ __launch_bounds__(256) void k_agg(
    const float* __restrict__ p, const float* __restrict__ x,
    const float* __restrict__ kp, const int* __restrict__ idx,
    __half* __restrict__ agg, int r0) {
  __shared__ float pj[4][16][4];
  __shared__ float co[4][16][16];
  const int l = threadIdx.x & 63;
  const int w = threadIdx.x >> 6;
  const int n = r0 + blockIdx.x * 4 + w;
  const int nc = (n < N_PTS) ? n : (N_PTS - 1);
  const int nbr = idx[nc * KNB + (l & 15)];         // lane l holds neighbor k=l&15

  // phase 0: relative coords + max-norm (lanes replicate per 16-group)
  const float cx = p[nc * 3], cy = p[nc * 3 + 1], cz = p[nc * 3 + 2];
  float ax = p[nbr * 3]     - cx;
  float ay = p[nbr * 3 + 1] - cy;
  float az = p[nbr * 3 + 2] - cz;
  float mx = sqrtf(ax * ax + ay * ay + az * az);
  #pragma unroll
  for (int d = 1; d < 16; d <<= 1) mx = fmaxf(mx, __shfl_xor(mx, d));
  const float inv = 1.0f / (mx + 1e-10f);
  ax *= inv; ay *= inv; az *= inv;

  // early-issue first 4 feature-row loads (latency hides under phases 0.5-1)
  #define LQ(K) (*(const float2*)(x + (size_t)(unsigned)__builtin_amdgcn_readlane(nbr, (K)) * CIN + 2 * l))
  float2 q0 = LQ(0), q1 = LQ(1), q2 = LQ(2), q3 = LQ(3);

  if (l < 16) { pj[w][l][0] = ax; pj[w][l][1] = ay; pj[w][l][2] = az; pj[w][l][3] = 0.f; }
  __syncthreads();

  // phase 1: corr for k=l>>2, m = (l&3)*4 + j  (m==15 -> 0)
  const int k1 = l >> 2;
  f32x4 pv = *(const f32x4*)&pj[w][k1][0];
  f32x4 cc;
  #pragma unroll
  for (int j = 0; j < 4; j++) {
    int m = (l & 3) * 4 + j;
    if (m < 15) {
      float dx = kp[m * 3] - pv[0], dy = kp[m * 3 + 1] - pv[1], dz = kp[m * 3 + 2] - pv[2];
      cc[j] = __expf((dx * dx + dy * dy + dz * dz) * -5.5555553f);
    } else cc[j] = 0.f;
  }
  *(f32x4*)&co[w][k1][(l & 3) * 4] = cc;            // for phase 3 column reads
  __syncthreads();

  int cb0 = __float_as_int(cc[0]), cb1 = __float_as_int(cc[1]);
  int cb2 = __float_as_int(cc[2]), cb3 = __float_as_int(cc[3]);

  // phase 2: accumulate over 16 neighbors; corr[(k,m)] lives in lane (k<<2)|(m>>2), reg m&3
  float a0[15], a1[15];
  #pragma unroll
  for (int m = 0; m < 15; m++) { a0[m] = 0.f; a1[m] = 0.f; }

  #define RL(REG, LANE) __int_as_float(__builtin_amdgcn_readlane(REG, LANE))
  #define COMP(K, Q) { _Pragma("unroll") for (int m = 0; m < 15; m++) {                \
      float cm;                                                                        \
      if ((m & 3) == 0) cm = RL(cb0, ((K) << 2) | (m >> 2));                           \
      else if ((m & 3) == 1) cm = RL(cb1, ((K) << 2) | (m >> 2));                      \
      else if ((m & 3) == 2) cm = RL(cb2, ((K) << 2) | (m >> 2));                      \
      else cm = RL(cb3, ((K) << 2) | (m >> 2));                                        \
      a0[m] += cm * (Q).x; a1[m] += cm * (Q).y; } }

  float2 n0, n1, n2, n3;
  n0 = LQ(4); n1 = LQ(5); n2 = LQ(6); n3 = LQ(7);
  COMP(0, q0) COMP(1, q1) COMP(2, q2) COMP(3, q3)
  q0 = n0; q1 = n1; q2 = n2; q3 = n3;
  n0 = LQ(8); n1 = LQ(9); n2 = LQ(10); n3 = LQ(11);
  COMP(4, q0) COMP(5, q1) COMP(6, q2) COMP(7, q3)
  q0 = n0; q1 = n1; q2 = n2; q3 = n3;
  n0 = LQ(12); n1 = LQ(13); n2 = LQ(14); n3 = LQ(15);
  COMP(8, q0) COMP(9, q1) COMP(10, q2) COMP(11, q3)
  q0 = n0; q1 = n1; q2 = n2; q3 = n3;
  COMP(12, q0) COMP(13, q1) COMP(14, q2) COMP(15, q3)

  if (n < N_PTS) {
    char* row = (char*)agg + (size_t)(n - r0) * (KP * 2);
    #pragma unroll
    for (int m = 0; m < 15; m++) {
      __half2 h = __floats2half2_rn(a0[m], a1[m]);  // cols m*136 + 2l, 2l+1
      __builtin_nontemporal_store(*(int*)&h, (int*)(row + MSTR * 2 * m + 4 * l));
    }
    // phase 3: pj-part (cols 128..130) + pads, lanes 0..15
    if (l < 15) {
      float s0 = 0.f, s1 = 0.f, s2 = 0.f;
      #pragma unroll
      for (int k = 0; k < 16; k++) {
        float cm = co[w][k][l];
        s0 += cm * pj[w][k][0]; s1 += cm * pj[w][k][1]; s2 += cm * pj[w][k][2];
      }
      __half2 h01 = __floats2half2_rn(s0, s1);
      __half2 h23 = __floats2half2_rn(s2, 0.f);
      i32x4 v; v.x = *(int*)&h01; v.y = *(int*)&h23; v.z = 0; v.w = 0;
      __builtin_nontemporal_store(v, (i32x4*)(row + MSTR * 2 * l + 256));
    } else if (l == 15) {
      i32x4 z = {0, 0, 0, 0};
      __builtin_nontemporal_store(z, (i32x4*)(row + 4080));  // cols 2040..2047
    }
  }
}

// ---------------- GEMM (2-phase dbuf): [rows,KP] x [COUT,KP]^T + BN + ReLU ----------------
__global__ __launch_bounds__(256) void k_gemm(
    const __half* __restrict__ A, const __half* __restrict__ B,
    const float* __restrict__ sc, const float* __restrict__ sh,
    float* __restrict__ out, int r0) {
  __shared__ __align__(16) __half Al[2][128 * 64];
  __shared__ __align__(16) __half Bl[2][128 * 64];
  const int t = threadIdx.x;
  const int l = t & 63;
  const int bn = blockIdx.x, bm = blockIdx.y;
  const int m0 = bm * 128, n0 = bn * 128;
  const int w = t >> 6;
  const int wm = w >> 1, wn = w & 1;

  f32x4 acc[4][4] = {};

  const int arow = t >> 3;
  const int kb   = (t & 7) << 4;
  const int kbsw = kb ^ ((arow & 7) << 4);
  const char* aSrc = (const char*)(A + (size_t)(m0 + arow) * KP) + kbsw;
  const char* bSrc = (const char*)(B + (size_t)(n0 + arow) * KP) + kbsw;
  const size_t rowStride32 = (size_t)32 * KP * 2;

  #define STAGE(BUF, KT) { _Pragma("unroll") for (int i = 0; i < 4; i++) {            \
      g2lds16(aSrc + i * rowStride32 + (size_t)(KT) * 128,                            \
              (char*)Al[BUF] + t * 16 + i * 4096);                                    \
      g2lds16(bSrc + i * rowStride32 + (size_t)(KT) * 128,                            \
              (char*)Bl[BUF] + t * 16 + i * 4096); } }

  STAGE(0, 0)
  __syncthreads();

  int buf = 0;
  for (int kt = 0; kt < KP / 64; kt++) {
    if (kt < KP / 64 - 1) STAGE(buf ^ 1, kt + 1)    // issue next tile early
    #pragma unroll
    for (int kk = 0; kk < 2; kk++) {
      f16x8 af[4], bf[4];
      const int rbyte = ((l >> 4) << 4) + kk * 64;
      #pragma unroll
      for (int i = 0; i < 4; i++) {
        const int ra = wm * 64 + i * 16 + (l & 15);
        af[i] = *(const f16x8*)((const char*)Al[buf] + ra * 128 + (rbyte ^ ((ra & 7) << 4)));
        const int rb = wn * 64 + i * 16 + (l & 15);
        bf[i] = *(const f16x8*)((const char*)Bl[buf] + rb * 128 + (rbyte ^ ((rb & 7) << 4)));
      }
      #pragma unroll
      for (int i = 0; i < 4; i++)
        #pragma unroll
        for (int j = 0; j < 4; j++)
          acc[i][j] = __builtin_amdgcn_mfma_f32_16x16x32_f16(af[i], bf[j], acc[i][j], 0, 0, 0);
    }
    __syncthreads();                                // drains vmcnt+lgkm, flips buffer
    buf ^= 1;
  }

  #pragma unroll
  for (int j = 0; j < 4; j++) {
    const int col = n0 + wn * 64 + j * 16 + (l & 15);
    const float s = sc[col], h = sh[col];
    #pragma unroll
    for (int i = 0; i < 4; i++) {
      const int rr = r0 + m0 + wm * 64 + i * 16 + ((l >> 4) << 2);
      #pragma unroll
      for (int rg = 0; rg < 4; rg++) {
        const int r = rr + rg;
        if (r < N_PTS) {
          float v = acc[i][j][rg] * s + h;
          out[(size_t)r * COUT + col] = fmaxf(v, 0.f);
        }
      }
    }
  }
}

extern "C" void kernel_launch(void* const* d_in, const int* in_sizes, int n_in,
                              void* d_out, int out_size, void* d_ws, size_t ws_size,
                              hipStream_t stream) {
  (void)in_sizes; (void)n_in; (void)out_size;
  const float* p   = (const float*)d_in[0];
  const float* x   = (const float*)d_in[1];
  const float* kp  = (const float*)d_in[2];
  const float* w   = (const float*)d_in[3];
  const float* cb  = (const float*)d_in[4];
  const float* g   = (const float*)d_in[5];
  const float* be  = (const float*)d_in[6];
  const float* mu  = (const float*)d_in[7];
  const float* var = (const float*)d_in[8];
  const int* idx   = (const int*)d_in[9];
  float* out = (float*)d_out;

  char* ws = (char*)d_ws;
  size_t off = 0;
  __half* wt  = (__half*)(ws + off); off += (size_t)COUT * KP * 2;   // 1 MB
  float*  sc  = (float*)(ws + off);  off += 1024;
  float*  sh  = (float*)(ws + off);  off += 1024;
  __half* agg = (__half*)(ws + off);
  size_t avail = (ws_size > off) ? (ws_size - off) : 0;

  size_t maxrows = avail / ((size_t)KP * 2);
  int rows;
  if (maxrows >= (size_t)MPAD) rows = MPAD;
  else rows = (int)(maxrows & ~(size_t)127);
  if (rows < 128) rows = 128;

  hipLaunchKernelGGL(k_prep_w, dim3(COUT * KP / 256), dim3(256), 0, stream,
                     w, cb, g, be, mu, var, wt, sc, sh);

  for (int row0 = 0; row0 < N_PTS; row0 += rows) {
    int rr = MPAD - row0;
    if (rr > rows) rr = rows;
    hipLaunchKernelGGL(k_agg, dim3(rr / 4), dim3(256), 0, stream, p, x, kp, idx, agg, row0);
    hipLaunchKernelGGL(k_gemm, dim3(2, rr / 128), dim3(256), 0, stream, agg, wt, sc, sh, out, row0);
  }
}

// Round 5
// 565.070 us; speedup vs baseline: 1.8545x; 1.1932x over previous
//
#include <hip/hip_runtime.h>
#include <hip/hip_fp16.h>

#define N_PTS   100000
#define KNB     16
#define CIN     128
#define COUT    256
#define NKP     15
#define CCH     131
#define MSTR    136          // per-kernel-point padded stride
#define KP      2048         // 15*136 = 2040, padded to 2048
#define MPAD    100096       // 782 * 128
#define CHROWS  25600        // rows per chunk (agg chunk = 104.9 MB -> L3-resident)

typedef _Float16 f16x8 __attribute__((ext_vector_type(8)));
typedef float    f32x4 __attribute__((ext_vector_type(4)));
typedef int      i32x4 __attribute__((ext_vector_type(4)));

__device__ __forceinline__ void g2lds16(const void* g, void* l) {
  __builtin_amdgcn_global_load_lds((const __attribute__((address_space(1))) void*)g,
                                   (__attribute__((address_space(3))) void*)l, 16, 0, 0);
}

// ---------------- prep: W repack + BN fold ----------------
__global__ __launch_bounds__(256) void k_prep_w(
    const float* __restrict__ w, const float* __restrict__ cb,
    const float* __restrict__ g, const float* __restrict__ be,
    const float* __restrict__ mu, const float* __restrict__ var,
    __half* __restrict__ wt, float* __restrict__ sc, float* __restrict__ sh) {
  int gid = blockIdx.x * 256 + threadIdx.x;
  int o = gid / KP, r = gid - o * KP;
  float v = 0.f;
  if (r < NKP * MSTR) {
    int m = r / MSTR, c = r - m * MSTR;
    if (c < 128)      v = w[(o * CCH + (c + 3)) * NKP + m];
    else if (c < 131) v = w[(o * CCH + (c - 128)) * NKP + m];
  }
  wt[gid] = __float2half(v);
  if (gid < COUT) {
    float s = g[gid] / sqrtf(var[gid] + 1e-5f);
    sc[gid] = s;
    sh[gid] = (cb[gid] - mu[gid]) * s + be[gid];
  }
}

// ---------------- agg: MFMA-based aggregation, one wave per point ----------------
// xj LDS tile [32 k][140 c] f16 (280B rows); agg[m][c] via mfma_f32_16x16x32_f16:
// A[m=lane&15][k=(l>>4)*8+i] = corr, B[k][c=c0+(lane&15)] = xj, D row=(l>>4)*4+i, col=lane&15.
#define XROW 140
__global__ __launch_bounds__(256) void k_agg(
    const float* __restrict__ p, const float* __restrict__ x,
    const float* __restrict__ kp, const int* __restrict__ idx,
    __half* __restrict__ agg, int r0) {
  __shared__ _Float16 xj[4][33 * XROW];   // +1 row slack for tail reads
  __shared__ float pj[4][16][4];
  __shared__ float co[4][16][16];         // co[k][m]
  const int l = threadIdx.x & 63;
  const int w = threadIdx.x >> 6;
  const int n = r0 + blockIdx.x * 4 + w;
  const int nc = (n < N_PTS) ? n : (N_PTS - 1);
  const int nbr = idx[nc * KNB + (l & 15)];

  // zero the xj tile (rows 16-31 stay zero; pad cols stay zero)
  {
    _Float16* xz = &xj[w][0];
    #pragma unroll
    for (int j = 0; j < 18; j++)
      *(f16x8*)(xz + (l + 64 * j) * 8 * 0 + 0) , (void)0;   // placeholder removed below
  }
  {
    char* xz = (char*)&xj[w][0];
    long2 z2 = {0, 0};
    #pragma unroll
    for (int j = 0; j < 18; j++)
      *(long*)(xz + 8 * (l + 64 * j)) = 0;                  // 64*18*8 = 9216B >= 32*280
  }

  // phase 0: relative coords + max-norm
  const float cx = p[nc * 3], cy = p[nc * 3 + 1], cz = p[nc * 3 + 2];
  float ax = p[nbr * 3]     - cx;
  float ay = p[nbr * 3 + 1] - cy;
  float az = p[nbr * 3 + 2] - cz;
  float mx = sqrtf(ax * ax + ay * ay + az * az);
  #pragma unroll
  for (int d = 1; d < 16; d <<= 1) mx = fmaxf(mx, __shfl_xor(mx, d));
  const float inv = 1.0f / (mx + 1e-10f);
  ax *= inv; ay *= inv; az *= inv;

  // gather neighbor features: lane owns channels 2l,2l+1; issue all 16 rows
  #define LQ(K) (*(const float2*)(x + (size_t)(unsigned)__builtin_amdgcn_readlane(nbr, (K)) * CIN + 2 * l))
  float2 q[16];
  #pragma unroll
  for (int k = 0; k < 16; k++) q[k] = LQ(k);

  if (l < 16) {
    pj[w][l][0] = ax; pj[w][l][1] = ay; pj[w][l][2] = az; pj[w][l][3] = 0.f;
    // pj into xj cols 128..130 of row k=l
    xj[w][l * XROW + 128] = (_Float16)ax;
    xj[w][l * XROW + 129] = (_Float16)ay;
    xj[w][l * XROW + 130] = (_Float16)az;
  }
  __syncthreads();

  // phase 1: corr for k=l>>2, m=(l&3)*4+j
  const int k1 = l >> 2;
  f32x4 pv = *(const f32x4*)&pj[w][k1][0];
  f32x4 cc;
  #pragma unroll
  for (int j = 0; j < 4; j++) {
    int m = (l & 3) * 4 + j;
    if (m < 15) {
      float dx = kp[m * 3] - pv[0], dy = kp[m * 3 + 1] - pv[1], dz = kp[m * 3 + 2] - pv[2];
      cc[j] = __expf((dx * dx + dy * dy + dz * dz) * -5.5555553f);
    } else cc[j] = 0.f;
  }
  *(f32x4*)&co[w][k1][(l & 3) * 4] = cc;

  // write gathered features into xj rows (f16 pairs, conflict-free: bank = l + 70k)
  #pragma unroll
  for (int k = 0; k < 16; k++) {
    __half2 h = __floats2half2_rn(q[k].x, q[k].y);
    *(__half2*)&xj[w][k * XROW + 2 * l] = h;
  }
  __syncthreads();

  // A-frag: corr[m=l&15][k=(l>>4)*8+i], lanes 0..31 (k<16); zero otherwise
  f16x8 af = {};
  if (l < 32) {
    #pragma unroll
    for (int i = 0; i < 8; i++)
      af[i] = (_Float16)co[w][(l >> 4) * 8 + i][l & 15];
  }

  const bool live = (n < N_PTS);
  __half* ar = agg + (size_t)(n - r0) * KP;
  const int cfix = l & 15;
  const int g4 = (l >> 4) * 4;

  #pragma unroll
  for (int c0 = 0; c0 <= 128; c0 += 16) {
    f16x8 bf = {};
    if (l < 32) {
      const _Float16* xb = &xj[w][(l >> 4) * 8 * XROW + c0 + cfix];
      #pragma unroll
      for (int i = 0; i < 8; i++) bf[i] = xb[i * XROW];
    }
    f32x4 d = __builtin_amdgcn_mfma_f32_16x16x32_f16(af, bf, (f32x4){0.f, 0.f, 0.f, 0.f}, 0, 0, 0);
    if (live) {
      const int c = c0 + cfix;
      #pragma unroll
      for (int i = 0; i < 4; i++) {
        const int m = g4 + i;
        if (m < 15 && c < 136)
          ar[m * MSTR + c] = __float2half(d[i]);
      }
    }
  }
  // zero pad cols 2040..2047
  if (live && l == 0) {
    i32x4 z = {0, 0, 0, 0};
    *(i32x4*)((char*)ar + 4080) = z;
  }
}

// ---------------- GEMM (single-buffer m97 structure): [rows,KP] x [COUT,KP]^T + BN + ReLU ----
__global__ __launch_bounds__(256) void k_gemm(
    const __half* __restrict__ A, const __half* __restrict__ B,
    const float* __restrict__ sc, const float* __restrict__ sh,
    float* __restrict__ out, int r0) {
  __shared__ __align__(16) __half Al[128 * 64];
  __shared__ __align__(16) __half Bl[128 * 64];
  const int t = threadIdx.x;
  const int l = t & 63;
  const int bn = blockIdx.x, bm = blockIdx.y;
  const int m0 = bm * 128, n0 = bn * 128;
  const int w = t >> 6;
  const int wm = w >> 1, wn = w & 1;

  f32x4 acc[4][4] = {};

  const int arow = t >> 3;
  const int kb   = (t & 7) << 4;
  const int kbsw = kb ^ ((arow & 7) << 4);
  const char* aSrc = (const char*)(A + (size_t)(m0 + arow) * KP) + kbsw;
  const char* bSrc = (const char*)(B + (size_t)(n0 + arow) * KP) + kbsw;
  char* aDst = (char*)Al + t * 16;
  char* bDst = (char*)Bl + t * 16;
  const size_t rowStride32 = (size_t)32 * KP * 2;

  for (int kt = 0; kt < KP / 64; kt++) {
    __syncthreads();
    #pragma unroll
    for (int i = 0; i < 4; i++) {
      g2lds16(aSrc + i * rowStride32 + (size_t)kt * 128, aDst + i * 4096);
      g2lds16(bSrc + i * rowStride32 + (size_t)kt * 128, bDst + i * 4096);
    }
    __syncthreads();
    #pragma unroll
    for (int kk = 0; kk < 2; kk++) {
      f16x8 af[4], bf[4];
      const int rbyte = ((l >> 4) << 4) + kk * 64;
      #pragma unroll
      for (int i = 0; i < 4; i++) {
        const int ra = wm * 64 + i * 16 + (l & 15);
        af[i] = *(const f16x8*)((const char*)Al + ra * 128 + (rbyte ^ ((ra & 7) << 4)));
        const int rb = wn * 64 + i * 16 + (l & 15);
        bf[i] = *(const f16x8*)((const char*)Bl + rb * 128 + (rbyte ^ ((rb & 7) << 4)));
      }
      #pragma unroll
      for (int i = 0; i < 4; i++)
        #pragma unroll
        for (int j = 0; j < 4; j++)
          acc[i][j] = __builtin_amdgcn_mfma_f32_16x16x32_f16(af[i], bf[j], acc[i][j], 0, 0, 0);
    }
  }

  #pragma unroll
  for (int j = 0; j < 4; j++) {
    const int col = n0 + wn * 64 + j * 16 + (l & 15);
    const float s = sc[col], h = sh[col];
    #pragma unroll
    for (int i = 0; i < 4; i++) {
      const int rr = r0 + m0 + wm * 64 + i * 16 + ((l >> 4) << 2);
      #pragma unroll
      for (int rg = 0; rg < 4; rg++) {
        const int r = rr + rg;
        if (r < N_PTS) {
          float v = acc[i][j][rg] * s + h;
          out[(size_t)r * COUT + col] = fmaxf(v, 0.f);
        }
      }
    }
  }
}

extern "C" void kernel_launch(void* const* d_in, const int* in_sizes, int n_in,
                              void* d_out, int out_size, void* d_ws, size_t ws_size,
                              hipStream_t stream) {
  (void)in_sizes; (void)n_in; (void)out_size;
  const float* p   = (const float*)d_in[0];
  const float* x   = (const float*)d_in[1];
  const float* kp  = (const float*)d_in[2];
  const float* w   = (const float*)d_in[3];
  const float* cb  = (const float*)d_in[4];
  const float* g   = (const float*)d_in[5];
  const float* be  = (const float*)d_in[6];
  const float* mu  = (const float*)d_in[7];
  const float* var = (const float*)d_in[8];
  const int* idx   = (const int*)d_in[9];
  float* out = (float*)d_out;

  char* ws = (char*)d_ws;
  size_t off = 0;
  __half* wt  = (__half*)(ws + off); off += (size_t)COUT * KP * 2;   // 1 MB
  float*  sc  = (float*)(ws + off);  off += 1024;
  float*  sh  = (float*)(ws + off);  off += 1024;
  __half* agg = (__half*)(ws + off);
  size_t avail = (ws_size > off) ? (ws_size - off) : 0;

  size_t maxrows = avail / ((size_t)KP * 2);
  int rows = CHROWS;                                  // L3-resident chunk
  if (maxrows < (size_t)rows) rows = (int)(maxrows & ~(size_t)127);
  if (rows < 128) rows = 128;

  hipLaunchKernelGGL(k_prep_w, dim3(COUT * KP / 256), dim3(256), 0, stream,
                     w, cb, g, be, mu, var, wt, sc, sh);

  for (int row0 = 0; row0 < N_PTS; row0 += rows) {
    int rr = MPAD - row0;
    if (rr > rows) rr = rows;
    hipLaunchKernelGGL(k_agg, dim3(rr / 4), dim3(256), 0, stream, p, x, kp, idx, agg, row0);
    hipLaunchKernelGGL(k_gemm, dim3(2, rr / 128), dim3(256), 0, stream, agg, wt, sc, sh, out, row0);
  }
}